// Round 10
// baseline (294.279 us; speedup 1.0000x reference)
//
#include <hip/hip_runtime.h>
#include <math.h>

#define NQ    20000
#define NV    19560
#define NHEAD 4
#define DEPTHD 64

typedef __attribute__((ext_vector_type(8))) short short8;
typedef __attribute__((ext_vector_type(4))) float f32x4;

__device__ __forceinline__ ushort f2bf(float f) {
    uint32_t u = __float_as_uint(f);
    uint32_t r = (u + 0x7FFFu + ((u >> 16) & 1u)) >> 16;
    return (ushort)r;
}
__device__ __forceinline__ float bf_lo(uint32_t d) { return __uint_as_float(d << 16); }
__device__ __forceinline__ float bf_hi(uint32_t d) { return __uint_as_float(d & 0xFFFF0000u); }

// ---------------------------------------------------------------------------
// Weight prep (proven form)
// ---------------------------------------------------------------------------
__global__ __launch_bounds__(256) void prep_weights(
    const float* __restrict__ Wv, const float* __restrict__ Wo,
    const float* __restrict__ Wod, const float* __restrict__ Wa,
    const float* __restrict__ bo, const float* __restrict__ bod,
    const float* __restrict__ ba,
    ushort* __restrict__ WvT, ushort* __restrict__ WqT, float* __restrict__ bq)
{
    const int b = blockIdx.x;
    const int k = threadIdx.x;
    if (b < 256) {
        WvT[b * 256 + k] = f2bf(Wv[k * 256 + b]);
    } else if (b < 768) {
        const int n = b - 256;
        float w;
        if (n < 256)      w = Wo [k * 256 + n];
        else if (n < 384) w = Wod[k * 128 + (n - 256)];
        else              w = Wa [k * 128 + (n - 384)];
        WqT[n * 256 + k] = f2bf(w);
    } else {
        for (int i = k; i < 512; i += 256) {
            float v;
            if (i < 256)      v = bo[i];
            else if (i < 384) v = bod[i - 256];
            else              v = ba[i - 384];
            bq[i] = v;
        }
    }
}

// ---------------------------------------------------------------------------
// dd4 table: dd4[z*NV + r] = uint2{ pack(d[r][z], d[r][z+1c]),
//                                   pack(d[r+1c][z], d[r+1c][z+1c]) }
// One aligned 8B load serves both x-corners of a point at plane z.
// Tiled through LDS: coalesced reads AND writes.
// ---------------------------------------------------------------------------
__global__ __launch_bounds__(256) void prep_dd4(
    const float* __restrict__ dd, uint2* __restrict__ dd4)
{
    __shared__ float tile[33][65];
    const int r0 = blockIdx.x * 32;
    for (int i = threadIdx.x; i < 33 * 64; i += 256) {
        const int rr = i >> 6, zz = i & 63;
        const int gr = min(r0 + rr, NV - 1);
        tile[rr][zz] = dd[(size_t)gr * 64 + zz];
    }
    __syncthreads();
    for (int i = threadIdx.x; i < 32 * 64; i += 256) {
        const int zz = i >> 5;
        const int rr = i & 31;
        if (r0 + rr < NV) {
            const int z1 = min(zz + 1, 63);
            uint2 o;
            o.x = (uint32_t)f2bf(tile[rr][zz])     | ((uint32_t)f2bf(tile[rr][z1])     << 16);
            o.y = (uint32_t)f2bf(tile[rr + 1][zz]) | ((uint32_t)f2bf(tile[rr + 1][z1]) << 16);
            dd4[(size_t)zz * NV + r0 + rr] = o;
        }
    }
}

// ---------------------------------------------------------------------------
// bf16 MFMA GEMM (proven): C = A(fp32) x BT(bf16)^T + bias.
// ---------------------------------------------------------------------------
template<bool BF16_OUT>
__global__ __launch_bounds__(256) void gemm_mfma_bf16(
    const float* __restrict__ A, const ushort* __restrict__ BT,
    const float* __restrict__ bias, void* __restrict__ Cout,
    int M, int ldc)
{
    constexpr int K = 256, BK = 32;
    __shared__ ushort Asb[128][40];
    __shared__ ushort Bsb[128][40];

    const int tid  = threadIdx.x;
    const int lane = tid & 63;
    const int wave = tid >> 6;
    const int wm   = wave >> 1;
    const int wn   = wave & 1;
    const int brow = blockIdx.y * 128;
    const int bcol = blockIdx.x * 128;
    const int l15  = lane & 15;
    const int kg   = lane >> 4;

    f32x4 acc[4][4] = {};

    const int rA    = tid >> 1;
    const int partA = tid & 1;

    for (int k0 = 0; k0 < K; k0 += BK) {
        {
            ushort tmp[16];
            if (brow + rA < M) {
                const float* ap = A + (size_t)(brow + rA) * K + k0 + partA * 16;
                #pragma unroll
                for (int i = 0; i < 4; ++i) {
                    float4 v = *reinterpret_cast<const float4*>(ap + i * 4);
                    tmp[i * 4 + 0] = f2bf(v.x);
                    tmp[i * 4 + 1] = f2bf(v.y);
                    tmp[i * 4 + 2] = f2bf(v.z);
                    tmp[i * 4 + 3] = f2bf(v.w);
                }
            } else {
                #pragma unroll
                for (int i = 0; i < 16; ++i) tmp[i] = 0;
            }
            *reinterpret_cast<uint4*>(&Asb[rA][partA * 16 + 0]) = *reinterpret_cast<uint4*>(tmp);
            *reinterpret_cast<uint4*>(&Asb[rA][partA * 16 + 8]) = *reinterpret_cast<uint4*>(tmp + 8);
        }
        #pragma unroll
        for (int i = 0; i < 2; ++i) {
            int f  = tid + i * 256;
            int n  = f >> 2;
            int c8 = (f & 3) * 8;
            uint4 v = *reinterpret_cast<const uint4*>(BT + (size_t)(bcol + n) * K + k0 + c8);
            *reinterpret_cast<uint4*>(&Bsb[n][c8]) = v;
        }
        __syncthreads();

        short8 af[4], bfv[4];
        #pragma unroll
        for (int mf = 0; mf < 4; ++mf)
            af[mf] = *reinterpret_cast<const short8*>(&Asb[wm * 64 + mf * 16 + l15][kg * 8]);
        #pragma unroll
        for (int nf = 0; nf < 4; ++nf)
            bfv[nf] = *reinterpret_cast<const short8*>(&Bsb[wn * 64 + nf * 16 + l15][kg * 8]);
        #pragma unroll
        for (int mf = 0; mf < 4; ++mf)
            #pragma unroll
            for (int nf = 0; nf < 4; ++nf)
                acc[mf][nf] = __builtin_amdgcn_mfma_f32_16x16x32_bf16(af[mf], bfv[nf], acc[mf][nf], 0, 0, 0);
        __syncthreads();
    }

    #pragma unroll
    for (int mf = 0; mf < 4; ++mf) {
        #pragma unroll
        for (int reg = 0; reg < 4; ++reg) {
            int row = brow + wm * 64 + mf * 16 + kg * 4 + reg;
            if (row >= M) continue;
            #pragma unroll
            for (int nf = 0; nf < 4; ++nf) {
                int col = bcol + wn * 64 + nf * 16 + l15;
                float v = acc[mf][nf][reg] + bias[col];
                if (BF16_OUT)
                    ((ushort*)Cout)[(size_t)row * ldc + col] = f2bf(v);
                else
                    ((float*)Cout)[(size_t)row * ldc + col] = v;
            }
        }
    }
}

// ---------------------------------------------------------------------------
// Sampler, 2 queries/block. Phase A: 2 aligned 8B dd4 gathers per point
// (was 4 dword). Phase B: 16 outstanding dwordx4 gathers enforced with
// sched_barrier fences; launch_bounds(256,4) caps VGPR at 128.
// ---------------------------------------------------------------------------
__device__ __forceinline__ void fma8(float* acc, float w, uint4 r) {
    acc[0] = fmaf(w, bf_lo(r.x), acc[0]);
    acc[1] = fmaf(w, bf_hi(r.x), acc[1]);
    acc[2] = fmaf(w, bf_lo(r.y), acc[2]);
    acc[3] = fmaf(w, bf_hi(r.y), acc[3]);
    acc[4] = fmaf(w, bf_lo(r.z), acc[4]);
    acc[5] = fmaf(w, bf_hi(r.z), acc[5]);
    acc[6] = fmaf(w, bf_lo(r.w), acc[6]);
    acc[7] = fmaf(w, bf_hi(r.w), acc[7]);
}

__global__ __launch_bounds__(256, 4) void deform_sample(
    const float* __restrict__ qproj,    // [NQ,512]
    const ushort* __restrict__ vproj,   // [NV,256] bf16
    const uint2* __restrict__ dd4,      // [64][NV] 4-tuple bf16
    const float* __restrict__ refpts,   // [NQ,4,3]
    float* __restrict__ out)            // [NQ,256]
{
    const int b    = blockIdx.x;
    const int h    = threadIdx.x >> 6;
    const int lane = threadIdx.x & 63;
    const int j    = lane & 31;
    const int qq   = lane >> 5;
    const int q    = 2 * b + qq;

    __shared__ float2 sm[NHEAD][2][128];

    const float* qrow = qproj + (size_t)q * 512;

    // ---- coords for point j of query q
    const int l  = j >> 3;
    const int p  = j & 7;
    const int zi = p & 3;
    const int Wl = 160 >> l;
    const int Hl = (l == 0) ? 92 : (l == 1) ? 46 : (l == 2) ? 23 : 12;
    const int st = (l == 0) ? 0  : (l == 1) ? 14720 : (l == 2) ? 18400 : 19320;

    const int oidx = (h * 4 + l) * 8 + p;
    const float ox = __builtin_nontemporal_load(qrow + oidx * 2 + 0);
    const float oy = __builtin_nontemporal_load(qrow + oidx * 2 + 1);
    const float od = __builtin_nontemporal_load(qrow + 256 + oidx);
    const float rx = refpts[(q * 4 + zi) * 3 + 0];
    const float ry = refpts[(q * 4 + zi) * 3 + 1];
    const float rz = refpts[(q * 4 + zi) * 3 + 2];

    const float x = fmaf(rx, (float)Wl, ox - 0.5f);
    const float y = fmaf(ry, (float)Hl, oy - 0.5f);
    const float z = fmaf(rz, 64.0f,     od - 0.5f);
    const float x0f = floorf(x), y0f = floorf(y), z0f = floorf(z);
    const float fx = x - x0f, fy = y - y0f, fz = z - z0f;
    const int x0 = (int)x0f, y0 = (int)y0f, z0 = (int)z0f;

    const int z0c = min(max(z0, 0), DEPTHD - 1);
    const float wlo = (z0 >= 0 && z0 <= 63) ? (1.f - fz) : ((z0 == -1) ? fz : 0.f);
    const float whi = (z0 >= 0 && z0 <= 62) ? fz : 0.f;

    // clamped rows / pair-base and selects
    const int yc0 = min(max(y0, 0), Hl - 1);
    const int yc1 = min(max(y0 + 1, 0), Hl - 1);
    const int xb  = min(max(x0, 0), Wl - 2);
    const int xc0 = min(max(x0, 0), Wl - 1);
    const int xc1 = min(max(x0 + 1, 0), Wl - 1);
    const int s0i = xc0 - xb;   // 0/1: which half of the pair
    const int s1i = xc1 - xb;

    // issue the two dd4 gathers early (independent of softmax)
    const uint2* plane = dd4 + (size_t)z0c * NV + st + xb;
    const uint2 u0 = plane[yc0 * Wl];
    const uint2 u1 = plane[yc1 * Wl];

    // ---- softmax over this query's 32 logits (independent of dd4 loads)
    float logit = __builtin_nontemporal_load(qrow + 384 + h * 32 + j);
    float m = logit;
    #pragma unroll
    for (int o = 16; o; o >>= 1) m = fmaxf(m, __shfl_xor(m, o));
    float e = __expf(logit - m);
    float s = e;
    #pragma unroll
    for (int o = 16; o; o >>= 1) s += __shfl_xor(s, o);
    const float aw = e / s;

    const float wx0 = 1.f - fx, wx1 = fx;
    const float wy0 = 1.f - fy, wy1 = fy;
    const bool vx0 = (x0 >= 0) & (x0 < Wl);
    const bool vx1 = (x0 + 1 >= 0) & (x0 + 1 < Wl);
    const bool vy0 = (y0 >= 0) & (y0 < Hl);
    const bool vy1 = (y0 + 1 >= 0) & (y0 + 1 < Hl);

    const uint32_t pd00 = s0i ? u0.y : u0.x;
    const uint32_t pd01 = s1i ? u0.y : u0.x;
    const uint32_t pd10 = s0i ? u1.y : u1.x;
    const uint32_t pd11 = s1i ? u1.y : u1.x;

    const int r00 = st + yc0 * Wl + xc0;
    const int r01 = st + yc0 * Wl + xc1;
    const int r10 = st + yc1 * Wl + xc0;
    const int r11 = st + yc1 * Wl + xc1;

    {
        const float ds00 = wlo * bf_lo(pd00) + whi * bf_hi(pd00);
        const float ds01 = wlo * bf_lo(pd01) + whi * bf_hi(pd01);
        const float ds10 = wlo * bf_lo(pd10) + whi * bf_hi(pd10);
        const float ds11 = wlo * bf_lo(pd11) + whi * bf_hi(pd11);
        const float c00 = (vx0 && vy0) ? (aw * wx0 * wy0 * ds00) : 0.f;
        const float c01 = (vx1 && vy0) ? (aw * wx1 * wy0 * ds01) : 0.f;
        const float c10 = (vx0 && vy1) ? (aw * wx0 * wy1 * ds10) : 0.f;
        const float c11 = (vx1 && vy1) ? (aw * wx1 * wy1 * ds11) : 0.f;
        sm[h][qq][0 * 32 + j] = make_float2(c00, __int_as_float(r00 * 512 + h * 128));
        sm[h][qq][1 * 32 + j] = make_float2(c01, __int_as_float(r01 * 512 + h * 128));
        sm[h][qq][2 * 32 + j] = make_float2(c10, __int_as_float(r10 * 512 + h * 128));
        sm[h][qq][3 * 32 + j] = make_float2(c11, __int_as_float(r11 * 512 + h * 128));
    }
    // no barrier: wave-private LDS buffer

    // ---- phase B: 16 outstanding gathers, fenced so the scheduler keeps them
    const int g   = lane >> 3;
    const int ch8 = (lane & 7) << 3;
    const uint32_t chb = (uint32_t)(ch8 << 1);
    const char* vb = (const char*)vproj;
    const float2* s0 = sm[h][0];
    const float2* s1 = sm[h][1];

    float acc0[8] = {}, acc1[8] = {};
    uint4 rA[8], rB[8];

    #pragma unroll
    for (int t = 0; t < 8; ++t)
        rA[t] = *reinterpret_cast<const uint4*>(vb + ((uint32_t)__float_as_int(s0[t * 8 + g].y) + chb));
    #pragma unroll
    for (int t = 0; t < 8; ++t)
        rB[t] = *reinterpret_cast<const uint4*>(vb + ((uint32_t)__float_as_int(s1[t * 8 + g].y) + chb));
    __builtin_amdgcn_sched_barrier(0);

    #pragma unroll
    for (int t = 0; t < 8; ++t) {
        fma8(acc0, s0[t * 8 + g].x, rA[t]);
        rA[t] = *reinterpret_cast<const uint4*>(vb + ((uint32_t)__float_as_int(s0[(t + 8) * 8 + g].y) + chb));
    }
    __builtin_amdgcn_sched_barrier(0);

    #pragma unroll
    for (int t = 0; t < 8; ++t) {
        fma8(acc1, s1[t * 8 + g].x, rB[t]);
        rB[t] = *reinterpret_cast<const uint4*>(vb + ((uint32_t)__float_as_int(s1[(t + 8) * 8 + g].y) + chb));
    }
    __builtin_amdgcn_sched_barrier(0);

    #pragma unroll
    for (int t = 0; t < 8; ++t) fma8(acc0, s0[(t + 8) * 8 + g].x, rA[t]);
    #pragma unroll
    for (int t = 0; t < 8; ++t) fma8(acc1, s1[(t + 8) * 8 + g].x, rB[t]);

    #pragma unroll
    for (int o = 8; o <= 32; o <<= 1) {
        #pragma unroll
        for (int k = 0; k < 8; ++k) {
            acc0[k] += __shfl_xor(acc0[k], o);
            acc1[k] += __shfl_xor(acc1[k], o);
        }
    }

    if (g == 0) {
        float* op0 = out + (size_t)(2 * b) * 256 + h * 64 + ch8;
        f32x4 o00 = {acc0[0], acc0[1], acc0[2], acc0[3]};
        f32x4 o01 = {acc0[4], acc0[5], acc0[6], acc0[7]};
        __builtin_nontemporal_store(o00, reinterpret_cast<f32x4*>(op0));
        __builtin_nontemporal_store(o01, reinterpret_cast<f32x4*>(op0 + 4));
        float* op1 = op0 + 256;
        f32x4 o10 = {acc1[0], acc1[1], acc1[2], acc1[3]};
        f32x4 o11 = {acc1[4], acc1[5], acc1[6], acc1[7]};
        __builtin_nontemporal_store(o10, reinterpret_cast<f32x4*>(op1));
        __builtin_nontemporal_store(o11, reinterpret_cast<f32x4*>(op1 + 4));
    }
}

// ---------------------------------------------------------------------------
extern "C" void kernel_launch(void* const* d_in, const int* in_sizes, int n_in,
                              void* d_out, int out_size, void* d_ws, size_t ws_size,
                              hipStream_t stream)
{
    const float* query  = (const float*)d_in[0];
    const float* value  = (const float*)d_in[1];
    const float* ddist  = (const float*)d_in[2];
    const float* refpts = (const float*)d_in[3];
    const float* Wv  = (const float*)d_in[6];
    const float* bv  = (const float*)d_in[7];
    const float* Wo  = (const float*)d_in[8];
    const float* bo  = (const float*)d_in[9];
    const float* Wod = (const float*)d_in[10];
    const float* bod = (const float*)d_in[11];
    const float* Wa  = (const float*)d_in[12];
    const float* ba  = (const float*)d_in[13];
    float* out = (float*)d_out;

    char* ws = (char*)d_ws;
    ushort* vbuf = (ushort*)ws;                                   // 10,014,720 B
    float*  qbuf = (float*)(ws + 10014720);                       // 40,960,000 B
    ushort* WvT  = (ushort*)(ws + 10014720 + 40960000);           // 131,072 B
    ushort* WqT  = WvT + 256 * 256;                               // 262,144 B
    float*  bq   = (float*)(WqT + 512 * 256);                     // 2,048 B
    uint2*  dd4  = (uint2*)((char*)bq + 2048);                    // 10,014,720 B (~61.4 MB)

    dim3 blk(256);

    prep_weights<<<dim3(769), blk, 0, stream>>>(Wv, Wo, Wod, Wa, bo, bod, ba, WvT, WqT, bq);
    prep_dd4<<<dim3((NV + 31) / 32), blk, 0, stream>>>(ddist, dd4);

    gemm_mfma_bf16<true><<<dim3(2, (NV + 127) / 128), blk, 0, stream>>>(
        value, WvT, bv, vbuf, NV, 256);

    gemm_mfma_bf16<false><<<dim3(4, (NQ + 127) / 128), blk, 0, stream>>>(
        query, WqT, bq, qbuf, NQ, 512);

    deform_sample<<<dim3(NQ / 2), blk, 0, stream>>>(qbuf, vbuf, dd4, refpts, out);
}

// Round 11
// 152.713 us; speedup vs baseline: 1.9270x; 1.9270x over previous
//
#include <hip/hip_runtime.h>
#include <math.h>

#define NQ    20000
#define NV    19560
#define NHEAD 4
#define DEPTHD 64

typedef __attribute__((ext_vector_type(8))) short short8;
typedef __attribute__((ext_vector_type(4))) float f32x4;

__device__ __forceinline__ ushort f2bf(float f) {
    uint32_t u = __float_as_uint(f);
    uint32_t r = (u + 0x7FFFu + ((u >> 16) & 1u)) >> 16;
    return (ushort)r;
}
__device__ __forceinline__ float bf_lo(uint32_t d) { return __uint_as_float(d << 16); }
__device__ __forceinline__ float bf_hi(uint32_t d) { return __uint_as_float(d & 0xFFFF0000u); }

// ---------------------------------------------------------------------------
// Weight prep (proven form)
// ---------------------------------------------------------------------------
__global__ __launch_bounds__(256) void prep_weights(
    const float* __restrict__ Wv, const float* __restrict__ Wo,
    const float* __restrict__ Wod, const float* __restrict__ Wa,
    const float* __restrict__ bo, const float* __restrict__ bod,
    const float* __restrict__ ba,
    ushort* __restrict__ WvT, ushort* __restrict__ WqT, float* __restrict__ bq)
{
    const int b = blockIdx.x;
    const int k = threadIdx.x;
    if (b < 256) {
        WvT[b * 256 + k] = f2bf(Wv[k * 256 + b]);
    } else if (b < 768) {
        const int n = b - 256;
        float w;
        if (n < 256)      w = Wo [k * 256 + n];
        else if (n < 384) w = Wod[k * 128 + (n - 256)];
        else              w = Wa [k * 128 + (n - 384)];
        WqT[n * 256 + k] = f2bf(w);
    } else {
        for (int i = k; i < 512; i += 256) {
            float v;
            if (i < 256)      v = bo[i];
            else if (i < 384) v = bod[i - 256];
            else              v = ba[i - 384];
            bq[i] = v;
        }
    }
}

// ---------------------------------------------------------------------------
// dd4 table (proven r10): dd4[z*NV + r] = { pack(d[r][z],d[r][z1]),
//                                           pack(d[r+1][z],d[r+1][z1]) }
// ---------------------------------------------------------------------------
__global__ __launch_bounds__(256) void prep_dd4(
    const float* __restrict__ dd, uint2* __restrict__ dd4)
{
    __shared__ float tile[33][65];
    const int r0 = blockIdx.x * 32;
    for (int i = threadIdx.x; i < 33 * 64; i += 256) {
        const int rr = i >> 6, zz = i & 63;
        const int gr = min(r0 + rr, NV - 1);
        tile[rr][zz] = dd[(size_t)gr * 64 + zz];
    }
    __syncthreads();
    for (int i = threadIdx.x; i < 32 * 64; i += 256) {
        const int zz = i >> 5;
        const int rr = i & 31;
        if (r0 + rr < NV) {
            const int z1 = min(zz + 1, 63);
            uint2 o;
            o.x = (uint32_t)f2bf(tile[rr][zz])     | ((uint32_t)f2bf(tile[rr][z1])     << 16);
            o.y = (uint32_t)f2bf(tile[rr + 1][zz]) | ((uint32_t)f2bf(tile[rr + 1][z1]) << 16);
            dd4[(size_t)zz * NV + r0 + rr] = o;
        }
    }
}

// ---------------------------------------------------------------------------
// bf16 MFMA GEMM (proven): C = A(fp32) x BT(bf16)^T + bias.
// ---------------------------------------------------------------------------
template<bool BF16_OUT>
__global__ __launch_bounds__(256) void gemm_mfma_bf16(
    const float* __restrict__ A, const ushort* __restrict__ BT,
    const float* __restrict__ bias, void* __restrict__ Cout,
    int M, int ldc)
{
    constexpr int K = 256, BK = 32;
    __shared__ ushort Asb[128][40];
    __shared__ ushort Bsb[128][40];

    const int tid  = threadIdx.x;
    const int lane = tid & 63;
    const int wave = tid >> 6;
    const int wm   = wave >> 1;
    const int wn   = wave & 1;
    const int brow = blockIdx.y * 128;
    const int bcol = blockIdx.x * 128;
    const int l15  = lane & 15;
    const int kg   = lane >> 4;

    f32x4 acc[4][4] = {};

    const int rA    = tid >> 1;
    const int partA = tid & 1;

    for (int k0 = 0; k0 < K; k0 += BK) {
        {
            ushort tmp[16];
            if (brow + rA < M) {
                const float* ap = A + (size_t)(brow + rA) * K + k0 + partA * 16;
                #pragma unroll
                for (int i = 0; i < 4; ++i) {
                    float4 v = *reinterpret_cast<const float4*>(ap + i * 4);
                    tmp[i * 4 + 0] = f2bf(v.x);
                    tmp[i * 4 + 1] = f2bf(v.y);
                    tmp[i * 4 + 2] = f2bf(v.z);
                    tmp[i * 4 + 3] = f2bf(v.w);
                }
            } else {
                #pragma unroll
                for (int i = 0; i < 16; ++i) tmp[i] = 0;
            }
            *reinterpret_cast<uint4*>(&Asb[rA][partA * 16 + 0]) = *reinterpret_cast<uint4*>(tmp);
            *reinterpret_cast<uint4*>(&Asb[rA][partA * 16 + 8]) = *reinterpret_cast<uint4*>(tmp + 8);
        }
        #pragma unroll
        for (int i = 0; i < 2; ++i) {
            int f  = tid + i * 256;
            int n  = f >> 2;
            int c8 = (f & 3) * 8;
            uint4 v = *reinterpret_cast<const uint4*>(BT + (size_t)(bcol + n) * K + k0 + c8);
            *reinterpret_cast<uint4*>(&Bsb[n][c8]) = v;
        }
        __syncthreads();

        short8 af[4], bfv[4];
        #pragma unroll
        for (int mf = 0; mf < 4; ++mf)
            af[mf] = *reinterpret_cast<const short8*>(&Asb[wm * 64 + mf * 16 + l15][kg * 8]);
        #pragma unroll
        for (int nf = 0; nf < 4; ++nf)
            bfv[nf] = *reinterpret_cast<const short8*>(&Bsb[wn * 64 + nf * 16 + l15][kg * 8]);
        #pragma unroll
        for (int mf = 0; mf < 4; ++mf)
            #pragma unroll
            for (int nf = 0; nf < 4; ++nf)
                acc[mf][nf] = __builtin_amdgcn_mfma_f32_16x16x32_bf16(af[mf], bfv[nf], acc[mf][nf], 0, 0, 0);
        __syncthreads();
    }

    #pragma unroll
    for (int mf = 0; mf < 4; ++mf) {
        #pragma unroll
        for (int reg = 0; reg < 4; ++reg) {
            int row = brow + wm * 64 + mf * 16 + kg * 4 + reg;
            if (row >= M) continue;
            #pragma unroll
            for (int nf = 0; nf < 4; ++nf) {
                int col = bcol + wn * 64 + nf * 16 + l15;
                float v = acc[mf][nf][reg] + bias[col];
                if (BF16_OUT)
                    ((ushort*)Cout)[(size_t)row * ldc + col] = f2bf(v);
                else
                    ((float*)Cout)[(size_t)row * ldc + col] = v;
            }
        }
    }
}

// ---------------------------------------------------------------------------
// Sampler, 2 queries/block. DEPENDENCY-SPLIT LDS: smoff (v-gather addresses,
// available right after coord math) is written BEFORE softmax/ddist work,
// and the first 16 v-gathers are issued immediately after — overlapping
// their latency with softmax + dd4. smcoef lands later; drain reads it.
// No sched fences (r10 lesson: they cause scratch spills).
// ---------------------------------------------------------------------------
__device__ __forceinline__ void fma8(float* acc, float w, uint4 r) {
    acc[0] = fmaf(w, bf_lo(r.x), acc[0]);
    acc[1] = fmaf(w, bf_hi(r.x), acc[1]);
    acc[2] = fmaf(w, bf_lo(r.y), acc[2]);
    acc[3] = fmaf(w, bf_hi(r.y), acc[3]);
    acc[4] = fmaf(w, bf_lo(r.z), acc[4]);
    acc[5] = fmaf(w, bf_hi(r.z), acc[5]);
    acc[6] = fmaf(w, bf_lo(r.w), acc[6]);
    acc[7] = fmaf(w, bf_hi(r.w), acc[7]);
}

__global__ __launch_bounds__(256, 2) void deform_sample(
    const float* __restrict__ qproj,    // [NQ,512]
    const ushort* __restrict__ vproj,   // [NV,256] bf16
    const uint2* __restrict__ dd4,      // [64][NV]
    const float* __restrict__ refpts,   // [NQ,4,3]
    float* __restrict__ out)            // [NQ,256]
{
    const int b    = blockIdx.x;
    const int h    = threadIdx.x >> 6;
    const int lane = threadIdx.x & 63;
    const int j    = lane & 31;
    const int qq   = lane >> 5;
    const int q    = 2 * b + qq;

    __shared__ uint32_t smoff [NHEAD][2][128];
    __shared__ float    smcoef[NHEAD][2][128];

    const float* qrow = qproj + (size_t)q * 512;

    // ---- early independent loads
    const float logit = qrow[384 + h * 32 + j];

    const int l  = j >> 3;
    const int p  = j & 7;
    const int zi = p & 3;
    const int Wl = 160 >> l;
    const int Hl = (l == 0) ? 92 : (l == 1) ? 46 : (l == 2) ? 23 : 12;
    const int st = (l == 0) ? 0  : (l == 1) ? 14720 : (l == 2) ? 18400 : 19320;

    const int oidx = (h * 4 + l) * 8 + p;
    const float ox = qrow[oidx * 2 + 0];
    const float oy = qrow[oidx * 2 + 1];
    const float od = qrow[256 + oidx];
    const float rx = refpts[(q * 4 + zi) * 3 + 0];
    const float ry = refpts[(q * 4 + zi) * 3 + 1];
    const float rz = refpts[(q * 4 + zi) * 3 + 2];

    const float x = fmaf(rx, (float)Wl, ox - 0.5f);
    const float y = fmaf(ry, (float)Hl, oy - 0.5f);
    const float z = fmaf(rz, 64.0f,     od - 0.5f);
    const float x0f = floorf(x), y0f = floorf(y), z0f = floorf(z);
    const float fx = x - x0f, fy = y - y0f, fz = z - z0f;
    const int x0 = (int)x0f, y0 = (int)y0f, z0 = (int)z0f;

    const int z0c = min(max(z0, 0), DEPTHD - 1);
    const float wlo = (z0 >= 0 && z0 <= 63) ? (1.f - fz) : ((z0 == -1) ? fz : 0.f);
    const float whi = (z0 >= 0 && z0 <= 62) ? fz : 0.f;

    const int yc0 = min(max(y0, 0), Hl - 1);
    const int yc1 = min(max(y0 + 1, 0), Hl - 1);
    const int xb  = min(max(x0, 0), Wl - 2);
    const int xc0 = min(max(x0, 0), Wl - 1);
    const int xc1 = min(max(x0 + 1, 0), Wl - 1);
    const int s0i = xc0 - xb;
    const int s1i = xc1 - xb;

    // issue dd4 gathers early
    const uint2* plane = dd4 + (size_t)z0c * NV + st + xb;
    const uint2 u0 = plane[yc0 * Wl];
    const uint2 u1 = plane[yc1 * Wl];

    // ---- addresses ready NOW: write smoff before any softmax/dscore work
    const int r00 = st + yc0 * Wl + xc0;
    const int r01 = st + yc0 * Wl + xc1;
    const int r10 = st + yc1 * Wl + xc0;
    const int r11 = st + yc1 * Wl + xc1;
    smoff[h][qq][0 * 32 + j] = (uint32_t)(r00 * 512 + h * 128);
    smoff[h][qq][1 * 32 + j] = (uint32_t)(r01 * 512 + h * 128);
    smoff[h][qq][2 * 32 + j] = (uint32_t)(r10 * 512 + h * 128);
    smoff[h][qq][3 * 32 + j] = (uint32_t)(r11 * 512 + h * 128);

    // ---- phase B issue: first 16 v-gathers, overlapping softmax/dd4 latency
    const int g   = lane >> 3;
    const int ch8 = (lane & 7) << 3;
    const uint32_t chb = (uint32_t)(ch8 << 1);
    const char* vb = (const char*)vproj;
    const uint32_t* o0 = smoff[h][0];
    const uint32_t* o1 = smoff[h][1];

    uint4 rA[8], rB[8];
    #pragma unroll
    for (int t = 0; t < 8; ++t)
        rA[t] = *reinterpret_cast<const uint4*>(vb + (o0[t * 8 + g] + chb));
    #pragma unroll
    for (int t = 0; t < 8; ++t)
        rB[t] = *reinterpret_cast<const uint4*>(vb + (o1[t * 8 + g] + chb));

    // ---- softmax (shuffle chain; v-gathers in flight)
    float m = logit;
    #pragma unroll
    for (int o = 16; o; o >>= 1) m = fmaxf(m, __shfl_xor(m, o));
    float e = __expf(logit - m);
    float s = e;
    #pragma unroll
    for (int o = 16; o; o >>= 1) s += __shfl_xor(s, o);
    const float aw = e / s;

    // ---- dscore + coefs
    const float wx0 = 1.f - fx, wx1 = fx;
    const float wy0 = 1.f - fy, wy1 = fy;
    const bool vx0 = (x0 >= 0) & (x0 < Wl);
    const bool vx1 = (x0 + 1 >= 0) & (x0 + 1 < Wl);
    const bool vy0 = (y0 >= 0) & (y0 < Hl);
    const bool vy1 = (y0 + 1 >= 0) & (y0 + 1 < Hl);

    const uint32_t pd00 = s0i ? u0.y : u0.x;
    const uint32_t pd01 = s1i ? u0.y : u0.x;
    const uint32_t pd10 = s0i ? u1.y : u1.x;
    const uint32_t pd11 = s1i ? u1.y : u1.x;

    const float ds00 = wlo * bf_lo(pd00) + whi * bf_hi(pd00);
    const float ds01 = wlo * bf_lo(pd01) + whi * bf_hi(pd01);
    const float ds10 = wlo * bf_lo(pd10) + whi * bf_hi(pd10);
    const float ds11 = wlo * bf_lo(pd11) + whi * bf_hi(pd11);
    smcoef[h][qq][0 * 32 + j] = (vx0 && vy0) ? (aw * wx0 * wy0 * ds00) : 0.f;
    smcoef[h][qq][1 * 32 + j] = (vx1 && vy0) ? (aw * wx1 * wy0 * ds01) : 0.f;
    smcoef[h][qq][2 * 32 + j] = (vx0 && vy1) ? (aw * wx0 * wy1 * ds10) : 0.f;
    smcoef[h][qq][3 * 32 + j] = (vx1 && vy1) ? (aw * wx1 * wy1 * ds11) : 0.f;
    // no barrier anywhere: all LDS is wave-private

    // ---- phase B drain + reissue
    const float* c0 = smcoef[h][0];
    const float* c1 = smcoef[h][1];

    float acc0[8] = {}, acc1[8] = {};
    #pragma unroll
    for (int t = 0; t < 8; ++t) {
        fma8(acc0, c0[t * 8 + g], rA[t]);
        rA[t] = *reinterpret_cast<const uint4*>(vb + (o0[(t + 8) * 8 + g] + chb));
    }
    #pragma unroll
    for (int t = 0; t < 8; ++t) {
        fma8(acc1, c1[t * 8 + g], rB[t]);
        rB[t] = *reinterpret_cast<const uint4*>(vb + (o1[(t + 8) * 8 + g] + chb));
    }
    #pragma unroll
    for (int t = 0; t < 8; ++t) fma8(acc0, c0[(t + 8) * 8 + g], rA[t]);
    #pragma unroll
    for (int t = 0; t < 8; ++t) fma8(acc1, c1[(t + 8) * 8 + g], rB[t]);

    #pragma unroll
    for (int o = 8; o <= 32; o <<= 1) {
        #pragma unroll
        for (int k = 0; k < 8; ++k) {
            acc0[k] += __shfl_xor(acc0[k], o);
            acc1[k] += __shfl_xor(acc1[k], o);
        }
    }

    if (g == 0) {
        float* op0 = out + (size_t)(2 * b) * 256 + h * 64 + ch8;
        f32x4 o00 = {acc0[0], acc0[1], acc0[2], acc0[3]};
        f32x4 o01 = {acc0[4], acc0[5], acc0[6], acc0[7]};
        __builtin_nontemporal_store(o00, reinterpret_cast<f32x4*>(op0));
        __builtin_nontemporal_store(o01, reinterpret_cast<f32x4*>(op0 + 4));
        float* op1 = op0 + 256;
        f32x4 o10 = {acc1[0], acc1[1], acc1[2], acc1[3]};
        f32x4 o11 = {acc1[4], acc1[5], acc1[6], acc1[7]};
        __builtin_nontemporal_store(o10, reinterpret_cast<f32x4*>(op1));
        __builtin_nontemporal_store(o11, reinterpret_cast<f32x4*>(op1 + 4));
    }
}

// ---------------------------------------------------------------------------
extern "C" void kernel_launch(void* const* d_in, const int* in_sizes, int n_in,
                              void* d_out, int out_size, void* d_ws, size_t ws_size,
                              hipStream_t stream)
{
    const float* query  = (const float*)d_in[0];
    const float* value  = (const float*)d_in[1];
    const float* ddist  = (const float*)d_in[2];
    const float* refpts = (const float*)d_in[3];
    const float* Wv  = (const float*)d_in[6];
    const float* bv  = (const float*)d_in[7];
    const float* Wo  = (const float*)d_in[8];
    const float* bo  = (const float*)d_in[9];
    const float* Wod = (const float*)d_in[10];
    const float* bod = (const float*)d_in[11];
    const float* Wa  = (const float*)d_in[12];
    const float* ba  = (const float*)d_in[13];
    float* out = (float*)d_out;

    char* ws = (char*)d_ws;
    ushort* vbuf = (ushort*)ws;                                   // 10,014,720 B
    float*  qbuf = (float*)(ws + 10014720);                       // 40,960,000 B
    ushort* WvT  = (ushort*)(ws + 10014720 + 40960000);           // 131,072 B
    ushort* WqT  = WvT + 256 * 256;                               // 262,144 B
    float*  bq   = (float*)(WqT + 512 * 256);                     // 2,048 B
    uint2*  dd4  = (uint2*)((char*)bq + 2048);                    // 10,014,720 B

    dim3 blk(256);

    prep_weights<<<dim3(769), blk, 0, stream>>>(Wv, Wo, Wod, Wa, bo, bod, ba, WvT, WqT, bq);
    prep_dd4<<<dim3((NV + 31) / 32), blk, 0, stream>>>(ddist, dd4);

    gemm_mfma_bf16<true><<<dim3(2, (NV + 127) / 128), blk, 0, stream>>>(
        value, WvT, bv, vbuf, NV, 256);

    gemm_mfma_bf16<false><<<dim3(4, (NQ + 127) / 128), blk, 0, stream>>>(
        query, WqT, bq, qbuf, NQ, 512);

    deform_sample<<<dim3(NQ / 2), blk, 0, stream>>>(qbuf, vbuf, dd4, refpts, out);
}